// Round 2
// baseline (301.147 us; speedup 1.0000x reference)
//
#include <hip/hip_runtime.h>

// Multi-head attention, B=4 S=2048 D=768 H=8 DH=96. FP32 I/O, f16 MFMA compute.
// R10: (a) attn rewritten 256thr/4 waves, 32 q-rows per wave (2 mf groups):
//      halves LDS reads per MFMA (K/V fragment reuse). Same LDS total (45.6KB),
//      same grid (16,32).
//      (b) Xq converted to f16 in prep too (guarded by ws_size >= 55.05MB);
//      gemm_qkv z=0 then uses the gll16 path like z=1,2. Runtime fallback to
//      fp32-staged path if ws is too small.
// Buffers: ws = [WqT|WkT|WvT|WoT (4.7MB) | Q16 | Xk16 | Xv16 | Xq16 (50.3MB)]
//          d_out = [VT (12.6MB) | K16 (12.6MB)] until GEMM_O overwrites (fp32)
//          A16 -> Xq buffer (dead after QKV GEMM; harness restores d_in).

typedef unsigned short u16;
typedef _Float16 h16;
typedef h16 h16x8 __attribute__((ext_vector_type(8)));
typedef __fp16 fp16x2 __attribute__((ext_vector_type(2)));
typedef unsigned short u16x8 __attribute__((ext_vector_type(8)));
typedef unsigned short u16x4 __attribute__((ext_vector_type(4)));
typedef float f32x4 __attribute__((ext_vector_type(4)));

__device__ __forceinline__ u16 f2h(float f) {
  union { h16 h; u16 u; } c; c.h = (h16)f; return c.u;
}

__device__ __forceinline__ void gll16(const void* g, void* l) {
  __builtin_amdgcn_global_load_lds(
      (const __attribute__((address_space(1))) void*)g,
      (__attribute__((address_space(3))) void*)l, 16, 0, 0);
}

// ---------------------------------------------------------------------------
// prep: WqT/WkT/WvT [n=h*96+kk][d] from W[h][d][kk]; WoT [n][k] from Wo[k][n];
//       plus Xk16/Xv16[/Xq16] = f16(X) conversions (gll16 staging in gemm_qkv)
// grid: 1152 weight blocks + 3072 per converted tensor
// ---------------------------------------------------------------------------
__global__ __launch_bounds__(256) void prep_kernel(
    const float* __restrict__ Wq, const float* __restrict__ Wk,
    const float* __restrict__ Wv, const float* __restrict__ Wo,
    const float* __restrict__ Xk, const float* __restrict__ Xv,
    const float* __restrict__ Xq,
    u16* __restrict__ WqT, u16* __restrict__ WkT,
    u16* __restrict__ WvT, u16* __restrict__ WoT,
    u16* __restrict__ Xk16, u16* __restrict__ Xv16, u16* __restrict__ Xq16)
{
  const long gid = (long)blockIdx.x * 256 + threadIdx.x;
  if (gid >= 294912) {
    long i = gid - 294912;                 // 0 .. nx*786432-1
    const int t = (int)(i / 786432);       // 0: Xk  1: Xv  2: Xq
    const long e = (i % 786432) * 8;
    const float* src = (t == 0) ? Xk : (t == 1) ? Xv : Xq;
    u16* dst = (t == 0) ? Xk16 : (t == 1) ? Xv16 : Xq16;
    f32x4 a = *(const f32x4*)(&src[e]);
    f32x4 b = *(const f32x4*)(&src[e + 4]);
    u16x8 v;
    #pragma unroll
    for (int j = 0; j < 4; j++) { v[j] = f2h(a[j]); v[4 + j] = f2h(b[j]); }
    *(u16x8*)(&dst[e]) = v;
    return;
  }
  int idx = (int)gid * 8;
  int region = idx / 589824;
  int i = idx % 589824;
  int n = i / 768;
  int d = i % 768;
  u16x8 v;
  if (region == 3) {
    #pragma unroll
    for (int j = 0; j < 8; j++) v[j] = f2h(Wo[(size_t)(d + j) * 768 + n]);
    *(u16x8*)(&WoT[i]) = v;
  } else {
    int h = n / 96, kk = n % 96;
    const float* W = (region == 0) ? Wq : (region == 1) ? Wk : Wv;
    u16* T = (region == 0) ? WqT : (region == 1) ? WkT : WvT;
    #pragma unroll
    for (int j = 0; j < 8; j++) v[j] = f2h(W[(size_t)h * 73728 + (size_t)(d + j) * 96 + kk]);
    *(u16x8*)(&T[i]) = v;
  }
}

// ---------------------------------------------------------------------------
// Batched QKV GEMM. qfp32=0: all z use f16 A via global_load_lds (m97 path).
// qfp32=1: z=0 falls back to fp32 A staged with in-register cvt.
// BM=128 BN=64 BK=32, LDS stride 32 (12 KB).
// ---------------------------------------------------------------------------
#define GK 768

__global__ __launch_bounds__(256) void gemm_qkv(
    const float* __restrict__ XqF, const u16* __restrict__ Xq16,
    const u16* __restrict__ Xk16, const u16* __restrict__ Xv16,
    const u16* __restrict__ WT,
    const float* __restrict__ bq, const float* __restrict__ bk,
    const float* __restrict__ bv,
    u16* __restrict__ Q16, u16* __restrict__ K16, u16* __restrict__ VT,
    int qfp32)
{
  const int z = blockIdx.z;
  const u16* BT = WT + (size_t)z * 589824;
  const float* bias = (z == 0) ? bq : (z == 1) ? bk : bv;

  __shared__ __align__(16) u16 As[128 * 32];
  __shared__ __align__(16) u16 Bs[64 * 32];
  const int tid = threadIdx.x;
  const int wave = tid >> 6;
  const int lane = tid & 63;
  const int quad = lane >> 4;
  const int l16 = lane & 15;
  const int m0 = blockIdx.x * 128;
  const int n0 = blockIdx.y * 64;

  f32x4 acc[2][4];
  #pragma unroll
  for (int i = 0; i < 2; i++)
    #pragma unroll
    for (int j = 0; j < 4; j++) acc[i][j] = (f32x4){0.f, 0.f, 0.f, 0.f};

  if (z == 0 && qfp32) {
    // ---- fp32-staged fallback (Q projection) ----
    const float* A = XqF;
    const int ar = tid >> 2;          // 0..63
    const int ac = (tid & 3) * 8;     // 0,8,16,24

    f32x4 pf[4];
    u16x8 pb;
    {
      pf[0] = *(const f32x4*)(&A[(size_t)(m0 + ar) * GK + ac]);
      pf[1] = *(const f32x4*)(&A[(size_t)(m0 + ar) * GK + ac + 4]);
      pf[2] = *(const f32x4*)(&A[(size_t)(m0 + 64 + ar) * GK + ac]);
      pf[3] = *(const f32x4*)(&A[(size_t)(m0 + 64 + ar) * GK + ac + 4]);
      pb = *(const u16x8*)(&BT[(size_t)(n0 + ar) * GK + ac]);
    }

    for (int kt = 0; kt < 24; kt++) {
      u16x8 h0, h1;
      #pragma unroll
      for (int j = 0; j < 4; j++) {
        h0[j] = f2h(pf[0][j]); h0[4 + j] = f2h(pf[1][j]);
        h1[j] = f2h(pf[2][j]); h1[4 + j] = f2h(pf[3][j]);
      }
      *(u16x8*)(&As[ar * 32 + ac]) = h0;
      *(u16x8*)(&As[(64 + ar) * 32 + ac]) = h1;
      *(u16x8*)(&Bs[ar * 32 + ac]) = pb;
      __syncthreads();

      if (kt + 1 < 24) {
        const int k0 = (kt + 1) * 32;
        pf[0] = *(const f32x4*)(&A[(size_t)(m0 + ar) * GK + k0 + ac]);
        pf[1] = *(const f32x4*)(&A[(size_t)(m0 + ar) * GK + k0 + ac + 4]);
        pf[2] = *(const f32x4*)(&A[(size_t)(m0 + 64 + ar) * GK + k0 + ac]);
        pf[3] = *(const f32x4*)(&A[(size_t)(m0 + 64 + ar) * GK + k0 + ac + 4]);
        pb = *(const u16x8*)(&BT[(size_t)(n0 + ar) * GK + k0 + ac]);
      }

      h16x8 af[2], bf[4];
      #pragma unroll
      for (int mf = 0; mf < 2; mf++)
        af[mf] = *(const h16x8*)(&As[(wave * 32 + mf * 16 + l16) * 32 + quad * 8]);
      #pragma unroll
      for (int nf = 0; nf < 4; nf++)
        bf[nf] = *(const h16x8*)(&Bs[(nf * 16 + l16) * 32 + quad * 8]);
      #pragma unroll
      for (int mf = 0; mf < 2; mf++)
        #pragma unroll
        for (int nf = 0; nf < 4; nf++)
          acc[mf][nf] = __builtin_amdgcn_mfma_f32_16x16x32_f16(af[mf], bf[nf], acc[mf][nf], 0, 0, 0);

      if (kt + 1 < 24) __syncthreads();
    }
  } else {
    // ---- gll16 path (A already f16) ----
    const u16* A = (z == 0) ? Xq16 : (z == 1) ? Xk16 : Xv16;
    const int Lr = lane >> 2, Lc = (lane & 3) * 8;
    const u16* gA0 = A + (size_t)(m0 + wave * 32 + Lr) * GK + Lc;
    const u16* gA1 = gA0 + (size_t)16 * GK;
    const u16* gB  = BT + (size_t)(n0 + wave * 16 + Lr) * GK + Lc;
    u16* lA0 = &As[(wave * 32) * 32];
    u16* lA1 = &As[(wave * 32 + 16) * 32];
    u16* lB  = &Bs[(wave * 16) * 32];

    for (int kt = 0; kt < 24; kt++) {
      gll16(gA0, lA0);
      gll16(gA1, lA1);
      gll16(gB, lB);
      gA0 += 32; gA1 += 32; gB += 32;
      __syncthreads();

      h16x8 af[2], bf[4];
      #pragma unroll
      for (int mf = 0; mf < 2; mf++)
        af[mf] = *(const h16x8*)(&As[(wave * 32 + mf * 16 + l16) * 32 + quad * 8]);
      #pragma unroll
      for (int nf = 0; nf < 4; nf++)
        bf[nf] = *(const h16x8*)(&Bs[(nf * 16 + l16) * 32 + quad * 8]);
      #pragma unroll
      for (int mf = 0; mf < 2; mf++)
        #pragma unroll
        for (int nf = 0; nf < 4; nf++)
          acc[mf][nf] = __builtin_amdgcn_mfma_f32_16x16x32_f16(af[mf], bf[nf], acc[mf][nf], 0, 0, 0);
      __syncthreads();
    }
  }

  u16* Yr = (z == 0) ? Q16 : K16;
  #pragma unroll
  for (int nf = 0; nf < 4; nf++) {
    const int n = n0 + nf * 16 + l16;
    const float bv2 = bias[n];
    #pragma unroll
    for (int mf = 0; mf < 2; mf++) {
      const int m = m0 + wave * 32 + mf * 16 + quad * 4;
      if (z == 2) {
        const int b = m >> 11, s = m & 2047;
        u16x4 pk;
        #pragma unroll
        for (int r = 0; r < 4; r++) pk[r] = f2h(acc[mf][nf][r] + bv2);
        *(u16x4*)(&VT[(size_t)b * 768 * 2048 + (size_t)n * 2048 + s]) = pk;
      } else {
        #pragma unroll
        for (int r = 0; r < 4; r++)
          Yr[(size_t)(m + r) * GK + n] = f2h(acc[mf][nf][r] + bv2);
      }
    }
  }
}

// ---------------------------------------------------------------------------
// GEMM_O: out[8192][768] fp32 = A16[8192][768] f16 @ WoT + bo.
// m97-style gll16 staging (A already f16).
// ---------------------------------------------------------------------------
__global__ __launch_bounds__(256) void gemm_o(
    const u16* __restrict__ A, const u16* __restrict__ BT,
    const float* __restrict__ bias, float* __restrict__ Y)
{
  __shared__ __align__(16) u16 As[128 * 32];
  __shared__ __align__(16) u16 Bs[64 * 32];
  const int tid = threadIdx.x;
  const int wave = tid >> 6;
  const int lane = tid & 63;
  const int quad = lane >> 4;
  const int l16 = lane & 15;
  const int m0 = blockIdx.x * 128;
  const int n0 = blockIdx.y * 64;

  f32x4 acc[2][4];
  #pragma unroll
  for (int i = 0; i < 2; i++)
    #pragma unroll
    for (int j = 0; j < 4; j++) acc[i][j] = (f32x4){0.f, 0.f, 0.f, 0.f};

  const int Lr = lane >> 2, Lc = (lane & 3) * 8;
  const u16* gA0 = A + (size_t)(m0 + wave * 32 + Lr) * GK + Lc;
  const u16* gA1 = gA0 + (size_t)16 * GK;
  const u16* gB  = BT + (size_t)(n0 + wave * 16 + Lr) * GK + Lc;
  u16* lA0 = &As[(wave * 32) * 32];
  u16* lA1 = &As[(wave * 32 + 16) * 32];
  u16* lB  = &Bs[(wave * 16) * 32];

  for (int kt = 0; kt < 24; kt++) {
    gll16(gA0, lA0);
    gll16(gA1, lA1);
    gll16(gB, lB);
    gA0 += 32; gA1 += 32; gB += 32;
    __syncthreads();

    h16x8 af[2], bf[4];
    #pragma unroll
    for (int mf = 0; mf < 2; mf++)
      af[mf] = *(const h16x8*)(&As[(wave * 32 + mf * 16 + l16) * 32 + quad * 8]);
    #pragma unroll
    for (int nf = 0; nf < 4; nf++)
      bf[nf] = *(const h16x8*)(&Bs[(nf * 16 + l16) * 32 + quad * 8]);
    #pragma unroll
    for (int mf = 0; mf < 2; mf++)
      #pragma unroll
      for (int nf = 0; nf < 4; nf++)
        acc[mf][nf] = __builtin_amdgcn_mfma_f32_16x16x32_f16(af[mf], bf[nf], acc[mf][nf], 0, 0, 0);
    __syncthreads();
  }

  #pragma unroll
  for (int nf = 0; nf < 4; nf++) {
    const int n = n0 + nf * 16 + l16;
    const float bv = bias[n];
    #pragma unroll
    for (int mf = 0; mf < 2; mf++) {
      const int m = m0 + wave * 32 + mf * 16 + quad * 4;
      #pragma unroll
      for (int r = 0; r < 4; r++)
        Y[(size_t)(m + r) * GK + n] = acc[mf][nf][r] + bv;
    }
  }
}

// ---------------------------------------------------------------------------
// Flash attention, S^T formulation, V^T input. Q,K: [4][2048][768] f16;
// VT: [4][768][2048] f16. 256 thr / 4 waves, 128 q-rows/block; each wave owns
// 32 q-rows (2 mf groups of 16) -> each Ks/Vt LDS fragment feeds 2 MFMAs
// (halves LDS reads per FLOP vs 16-rows/wave). Register-pipelined staging;
// defer-max (T13, THR raw=54); setprio around MFMA (T5); l-sum in epilogue.
// LDS: Ks 13.3KB + Vt 13.8KB + Ps 18.4KB = 45.6KB.
// ---------------------------------------------------------------------------
#define SEQ 2048
#define LQK 104
#define LVT 72
#define LPS 72

__global__ __launch_bounds__(256) void attn_kernel(
    const u16* __restrict__ Q, const u16* __restrict__ K,
    const u16* __restrict__ VT, u16* __restrict__ O)
{
  __shared__ __align__(16) u16 Ks[64 * LQK];
  __shared__ __align__(16) u16 Vt[96 * LVT];
  __shared__ __align__(16) u16 Ps[4][32 * LPS];

  const int tid = threadIdx.x;
  const int wave = tid >> 6;
  const int lane = tid & 63;
  const int quad = lane >> 4;
  const int l16 = lane & 15;

  const int bh = blockIdx.y;
  const int b = bh >> 3, h = bh & 7;
  const int q0 = blockIdx.x * 128;

  const size_t batch_off = (size_t)b * SEQ * 768;
  const u16* Kg = K + batch_off + h * 96;
  const u16* Vg = VT + (size_t)b * 768 * 2048 + (size_t)(h * 96) * 2048;

  // Q fragments for this wave's 32 q-rows (2 groups of 16)
  h16x8 qf[2][3];
  #pragma unroll
  for (int mf = 0; mf < 2; mf++) {
    const u16* Qrow = Q + batch_off +
        (size_t)(q0 + wave * 32 + mf * 16 + l16) * 768 + h * 96 + quad * 8;
    #pragma unroll
    for (int ks = 0; ks < 3; ks++) qf[mf][ks] = *(const h16x8*)(&Qrow[ks * 32]);
  }

  // staging slots: K 64x96 = 768 u16x8 slots, V 96x64 = 768 slots; 3 each/thread
  int krr[3], kcc[3], vrr[3], vcc[3];
  #pragma unroll
  for (int j = 0; j < 3; j++) {
    const int ik = tid + j * 256;
    krr[j] = ik / 12; kcc[j] = (ik % 12) * 8;
    vrr[j] = ik >> 3; vcc[j] = (ik & 7) * 8;
  }

  f32x4 o[2][6];
  #pragma unroll
  for (int mf = 0; mf < 2; mf++)
    #pragma unroll
    for (int i = 0; i < 6; i++) o[mf][i] = (f32x4){0.f, 0.f, 0.f, 0.f};
  float m_raw[2] = {-1e30f, -1e30f};
  float lrow[2] = {0.f, 0.f};         // quad-partials; cross-quad in epilogue
  const float sc = 0.14724498f;       // log2(e)/sqrt(96)

  u16* Pw = &Ps[wave][0];

  u16x8 kA[3], vA[3];
  #pragma unroll
  for (int j = 0; j < 3; j++) {
    kA[j] = *(const u16x8*)(&Kg[(size_t)krr[j] * 768 + kcc[j]]);
    vA[j] = *(const u16x8*)(&Vg[(size_t)vrr[j] * 2048 + vcc[j]]);
  }

  for (int kt = 0; kt < SEQ / 64; kt++) {
    #pragma unroll
    for (int j = 0; j < 3; j++) {
      *(u16x8*)(&Ks[krr[j] * LQK + kcc[j]]) = kA[j];
      *(u16x8*)(&Vt[vrr[j] * LVT + vcc[j]]) = vA[j];
    }
    __syncthreads();

    if (kt + 1 < SEQ / 64) {
      const u16* Kn = Kg + (size_t)(kt + 1) * 64 * 768;
      const u16* Vn = Vg + (size_t)(kt + 1) * 64;
      #pragma unroll
      for (int j = 0; j < 3; j++) {
        kA[j] = *(const u16x8*)(&Kn[(size_t)krr[j] * 768 + kcc[j]]);
        vA[j] = *(const u16x8*)(&Vn[(size_t)vrr[j] * 2048 + vcc[j]]);
      }
    }

    // QK^T: A-frag (K-rows) read once, feeds both mf groups
    f32x4 s[2][4];
    #pragma unroll
    for (int mf = 0; mf < 2; mf++)
      #pragma unroll
      for (int kf = 0; kf < 4; kf++) s[mf][kf] = (f32x4){0.f, 0.f, 0.f, 0.f};
    __builtin_amdgcn_s_setprio(1);
    #pragma unroll
    for (int ks = 0; ks < 3; ks++) {
      #pragma unroll
      for (int kf = 0; kf < 4; kf++) {
        h16x8 a = *(const h16x8*)(&Ks[(kf * 16 + l16) * LQK + ks * 32 + quad * 8]);
        s[0][kf] = __builtin_amdgcn_mfma_f32_16x16x32_f16(a, qf[0][ks], s[0][kf], 0, 0, 0);
        s[1][kf] = __builtin_amdgcn_mfma_f32_16x16x32_f16(a, qf[1][ks], s[1][kf], 0, 0, 0);
      }
    }
    __builtin_amdgcn_s_setprio(0);

    #pragma unroll
    for (int mf = 0; mf < 2; mf++) {
      float mx = s[mf][0][0];
      #pragma unroll
      for (int kf = 0; kf < 4; kf++)
        #pragma unroll
        for (int r = 0; r < 4; r++) mx = fmaxf(mx, s[mf][kf][r]);
      mx = fmaxf(mx, __shfl_xor(mx, 16));
      mx = fmaxf(mx, __shfl_xor(mx, 32));
      // defer-max (T13): rescale only when max grew by > 54 raw
      // (sc*54=7.95 -> P <= 2^7.95, f16-safe; cancels in 1/lrow).
      if (__any(mx > m_raw[mf] + 54.0f)) {
        const float mnew = fmaxf(m_raw[mf], mx);
        const float alpha = exp2f(sc * (m_raw[mf] - mnew));  // 0 on first tile
        lrow[mf] *= alpha;
        #pragma unroll
        for (int nfo = 0; nfo < 6; nfo++)
          #pragma unroll
          for (int r = 0; r < 4; r++) o[mf][nfo][r] *= alpha;
        m_raw[mf] = mnew;
      }
      const float c0 = sc * m_raw[mf];
      float ps = 0.f;
      #pragma unroll
      for (int kf = 0; kf < 4; kf++)
        #pragma unroll
        for (int r = 0; r < 4; r++) {
          float p = exp2f(fmaf(s[mf][kf][r], sc, -c0));
          s[mf][kf][r] = p;
          ps += p;
        }
      lrow[mf] += ps;

      #pragma unroll
      for (int kf = 0; kf < 4; kf++)
        #pragma unroll
        for (int rp = 0; rp < 4; rp += 2) {
          fp16x2 pk = __builtin_amdgcn_cvt_pkrtz(s[mf][kf][rp], s[mf][kf][rp + 1]);
          *(fp16x2*)(&Pw[(mf * 16 + l16) * LPS + kf * 16 + quad * 4 + rp]) = pk;
        }
    }

    // PV: Vt fragment read once, feeds both mf groups
    __builtin_amdgcn_s_setprio(1);
    #pragma unroll
    for (int ks = 0; ks < 2; ks++) {
      h16x8 pf0 = *(const h16x8*)(&Pw[l16 * LPS + ks * 32 + quad * 8]);
      h16x8 pf1 = *(const h16x8*)(&Pw[(16 + l16) * LPS + ks * 32 + quad * 8]);
      #pragma unroll
      for (int nfo = 0; nfo < 6; nfo++) {
        h16x8 vfr = *(const h16x8*)(&Vt[(nfo * 16 + l16) * LVT + ks * 32 + quad * 8]);
        o[0][nfo] = __builtin_amdgcn_mfma_f32_16x16x32_f16(vfr, pf0, o[0][nfo], 0, 0, 0);
        o[1][nfo] = __builtin_amdgcn_mfma_f32_16x16x32_f16(vfr, pf1, o[1][nfo], 0, 0, 0);
      }
    }
    __builtin_amdgcn_s_setprio(0);
    __syncthreads();
  }

  #pragma unroll
  for (int mf = 0; mf < 2; mf++) {
    float l = lrow[mf];
    l += __shfl_xor(l, 16);
    l += __shfl_xor(l, 32);
    const float inv = 1.0f / l;
    u16* Ob = O + batch_off +
        (size_t)(q0 + wave * 32 + mf * 16 + l16) * 768 + h * 96;
    #pragma unroll
    for (int nfo = 0; nfo < 6; nfo++) {
      fp16x2 lo = __builtin_amdgcn_cvt_pkrtz(o[mf][nfo][0] * inv, o[mf][nfo][1] * inv);
      fp16x2 hi = __builtin_amdgcn_cvt_pkrtz(o[mf][nfo][2] * inv, o[mf][nfo][3] * inv);
      *(fp16x2*)(&Ob[nfo * 16 + quad * 4]) = lo;
      *(fp16x2*)(&Ob[nfo * 16 + quad * 4 + 2]) = hi;
    }
  }
}

// ---------------------------------------------------------------------------
extern "C" void kernel_launch(void* const* d_in, const int* in_sizes, int n_in,
                              void* d_out, int out_size, void* d_ws, size_t ws_size,
                              hipStream_t stream) {
  const float* Xq = (const float*)d_in[0];
  const float* Xk = (const float*)d_in[1];
  const float* Xv = (const float*)d_in[2];
  const float* Wq = (const float*)d_in[3];
  const float* bq = (const float*)d_in[4];
  const float* Wk = (const float*)d_in[5];
  const float* bk = (const float*)d_in[6];
  const float* Wv = (const float*)d_in[7];
  const float* bv = (const float*)d_in[8];
  const float* Wo = (const float*)d_in[9];
  const float* bo = (const float*)d_in[10];

  u16* wsu = (u16*)d_ws;
  u16* WT   = wsu;                    // WqT | WkT | WvT, 589824 each
  u16* WoT  = wsu + 3 * 589824;
  u16* Q16  = wsu + 4 * 589824;       // 12.6 MB
  u16* Xk16 = Q16 + 6291456;          // 12.6 MB
  u16* Xv16 = Xk16 + 6291456;         // 12.6 MB
  u16* Xq16 = Xv16 + 6291456;         // 12.6 MB (total 55.05 MB when used)

  // Xq16 path needs 55.05 MB of ws; fall back to fp32-staged Q GEMM otherwise.
  const size_t need = (size_t)(4 * 589824 + 4 * 6291456) * 2;
  const int q16 = (ws_size >= need) ? 1 : 0;
  const int nx = q16 ? 3 : 2;

  u16* outu = (u16*)d_out;
  u16* VTb = outu;                   // V^T f16 [4][768][2048]
  u16* K16 = outu + 6291456;         // K f16 rowmajor

  u16* A16 = (u16*)d_in[0];          // attn out (Xq dead after QKV GEMM)

  prep_kernel<<<1152 + 3072 * nx, 256, 0, stream>>>(
      Wq, Wk, Wv, Wo, Xk, Xv, Xq,
      WT, WT + 589824, WT + 2 * 589824, WoT, Xk16, Xv16, Xq16);
  gemm_qkv<<<dim3(64, 12, 3), 256, 0, stream>>>(
      Xq, Xq16, Xk16, Xv16, WT, bq, bk, bv, Q16, K16, VTb, q16 ? 0 : 1);
  attn_kernel<<<dim3(16, 32), 256, 0, stream>>>(Q16, K16, VTb, A16);
  gemm_o<<<dim3(64, 12), 256, 0, stream>>>(A16, WoT, bo, (float*)d_out);
}